// Round 4
// baseline (371.168 us; speedup 1.0000x reference)
//
#include <hip/hip_runtime.h>
#include <math.h>

// Match numpy's non-FMA evaluation of the distance formula (ranking fidelity).
#pragma clang fp contract(off)

#define NPTS 4096
#define KNN  16
#define RPW  2                    // rows per wave (amortize LDS Q-reads)
#define KWAVES 8                  // waves per knn block
#define KT   (KWAVES * 64)        // 512 threads
#define RPBK (KWAVES * RPW)       // 16 rows per block
#define CAP  128                  // filtered-candidate capacity per row

// ordered-uint transform: monotone map f32 -> u32 (canonicalize -0 -> +0 first)
__device__ __forceinline__ unsigned okey(float f) {
    f = f + 0.0f;
    unsigned u = __float_as_uint(f);
    return u ^ (((unsigned)((int)u >> 31)) | 0x80000000u);
}

__device__ __forceinline__ unsigned wmin32(unsigned v) {
    for (int o = 32; o > 0; o >>= 1) { unsigned w = __shfl_xor(v, o); v = w < v ? w : v; }
    return v;
}
__device__ __forceinline__ unsigned long long wmin64(unsigned long long v) {
    for (int o = 32; o > 0; o >>= 1) { unsigned long long w = __shfl_xor(v, o); v = w < v ? w : v; }
    return v;
}

// ---------------------------------------------------------------------------
// Dense fill of L: zeros + unit diagonal (256 MB stream). Also zeros Dsum
// (first 4096 threads) so no separate zero_kernel dispatch is needed.
// ---------------------------------------------------------------------------
__global__ __launch_bounds__(256) void fill_kernel(float4* __restrict__ L4,
                                                   float4* __restrict__ Dsum4,
                                                   size_t T4) {
    size_t g4     = (size_t)blockIdx.x * blockDim.x + threadIdx.x;
    size_t stride = (size_t)gridDim.x * blockDim.x;
    if (g4 < 4096) Dsum4[g4] = make_float4(0.f, 0.f, 0.f, 0.f);   // BN/4 = 4096
    for (; g4 < T4; g4 += stride) {
        size_t g = g4 << 2;
        int o    = (int)(g & (size_t)(NPTS * (size_t)NPTS - 1));  // N^2 = 2^24
        int row  = o >> 12;
        int col0 = o & (NPTS - 1);
        float4 v;
        v.x = (row == col0    ) ? 1.0f : 0.0f;
        v.y = (row == col0 + 1) ? 1.0f : 0.0f;
        v.z = (row == col0 + 2) ? 1.0f : 0.0f;
        v.w = (row == col0 + 3) ? 1.0f : 0.0f;
        L4[g4] = v;
    }
}

// ---------------------------------------------------------------------------
// KNN via threshold-filter + exact small select. One wave per RPW(=2) rows:
// each LDS Q-read is amortized over 2 rows (scan is LDS-pipe-bound).
// Selection key is lexicographic (okey(d2_formula), idx) == lax.top_k order.
// ---------------------------------------------------------------------------
__global__ __launch_bounds__(KT, 4) void knn_kernel(const float* __restrict__ xyz,
                                                    float* __restrict__ Dsum,
                                                    int* __restrict__ idx_out,
                                                    float* __restrict__ w_out) {
    __shared__ float4 spts[NPTS];            // 64 KB: (x,y,z,|p|^2)
    __shared__ int    lists[RPBK][CAP];      // 8 KB

    const int t    = threadIdx.x;
    const int lane = t & 63;
    const int wv   = t >> 6;
    const int row0 = blockIdx.x * RPBK + wv * RPW;        // first of this wave's rows
    const int b    = row0 >> 12;                          // block spans one batch
    const float* X = xyz + (size_t)b * 3 * NPTS;

    for (int i = t; i < NPTS; i += KT) {
        float x = X[i], y = X[NPTS + i], z = X[2 * NPTS + i];
        spts[i] = make_float4(x, y, z, (x * x + y * y) + z * z);   // numpy order
    }
    __syncthreads();

    const float4 P0 = spts[(row0 + 0) & (NPTS - 1)];
    const float4 P1 = spts[(row0 + 1) & (NPTS - 1)];

    // ---- phase 1: per-lane chunk minima; T = 16th smallest lane-min ----
    unsigned b0 = 0xFFFFFFFFu, b1 = 0xFFFFFFFFu;
    for (int i = 0; i < NPTS / 64; ++i) {
        float4 Q   = spts[i * 64 + lane];
        float dot0 = (P0.x * Q.x + P0.y * Q.y) + P0.z * Q.z;       // einsum order
        float dot1 = (P1.x * Q.x + P1.y * Q.y) + P1.z * Q.z;
        unsigned k0 = okey((P0.w + Q.w) - 2.0f * dot0);            // (sq+sq)-2dot
        unsigned k1 = okey((P1.w + Q.w) - 2.0f * dot1);
        b0 = k0 < b0 ? k0 : b0;
        b1 = k1 < b1 ? k1 : b1;
    }
    unsigned T0 = 0, T1 = 0;
    {
        unsigned cur = b0;
        for (int r = 0; r < KNN; ++r) { unsigned mn = wmin32(cur); T0 = mn; if (cur == mn) cur = 0xFFFFFFFFu; }
        cur = b1;
        for (int r = 0; r < KNN; ++r) { unsigned mn = wmin32(cur); T1 = mn; if (cur == mn) cur = 0xFFFFFFFFu; }
    }

    // ---- phase 2: filter candidates with key <= T into LDS lists ----
    int cnt0 = 0, cnt1 = 0;
    for (int i = 0; i < NPTS / 64; ++i) {
        int m = i * 64 + lane;
        float4 Q   = spts[m];
        float dot0 = (P0.x * Q.x + P0.y * Q.y) + P0.z * Q.z;
        float dot1 = (P1.x * Q.x + P1.y * Q.y) + P1.z * Q.z;
        bool p0 = okey((P0.w + Q.w) - 2.0f * dot0) <= T0;
        bool p1 = okey((P1.w + Q.w) - 2.0f * dot1) <= T1;
        unsigned long long bal0 = __ballot(p0);
        unsigned long long bal1 = __ballot(p1);
        if (p0) {
            int pos = cnt0 + __popcll(bal0 & ((1ull << lane) - 1ull));
            if (pos < CAP) lists[wv * RPW + 0][pos] = m;
        }
        if (p1) {
            int pos = cnt1 + __popcll(bal1 & ((1ull << lane) - 1ull));
            if (pos < CAP) lists[wv * RPW + 1][pos] = m;
        }
        cnt0 += (int)__popcll(bal0);
        cnt1 += (int)__popcll(bal1);
    }

    // ---- phase 3 + outputs, per row ----
    for (int r = 0; r < RPW; ++r) {
        const int rowg = row0 + r;
        const float4 P = r == 0 ? P0 : P1;
        const int cnt  = r == 0 ? cnt0 : cnt1;
        const int lr   = wv * RPW + r;

        unsigned long long sel = ~0ull;
        if (cnt <= CAP) {
            unsigned long long e0 = ~0ull, e1 = ~0ull;
            if (lane < cnt) {
                int m = lists[lr][lane]; float4 Q = spts[m];
                float dot = (P.x * Q.x + P.y * Q.y) + P.z * Q.z;
                float d2  = (P.w + Q.w) - 2.0f * dot;
                e0 = ((unsigned long long)okey(d2) << 32) | (unsigned)m;
            }
            if (lane + 64 < cnt) {
                int m = lists[lr][lane + 64]; float4 Q = spts[m];
                float dot = (P.x * Q.x + P.y * Q.y) + P.z * Q.z;
                float d2  = (P.w + Q.w) - 2.0f * dot;
                e1 = ((unsigned long long)okey(d2) << 32) | (unsigned)m;
            }
            unsigned long long c = e0 < e1 ? e0 : e1;
            for (int k = 0; k < KNN; ++k) {
                unsigned long long mn = wmin64(c);
                if (c == mn) {                      // keys unique -> one lane
                    if (e0 == mn) e0 = ~0ull; else e1 = ~0ull;
                    c = e0 < e1 ? e0 : e1;
                }
                if (lane == k) sel = mn;
            }
        } else {
            // overflow fallback (astronomically rare): exact 16 rounds of
            // strictly-increasing wave-min over the full candidate set
            unsigned long long last = 0;
            for (int k = 0; k < KNN; ++k) {
                unsigned long long bestp = ~0ull;
                for (int i = 0; i < NPTS / 64; ++i) {
                    int m = i * 64 + lane;
                    float4 Q  = spts[m];
                    float dot = (P.x * Q.x + P.y * Q.y) + P.z * Q.z;
                    float d2  = (P.w + Q.w) - 2.0f * dot;
                    unsigned long long key = ((unsigned long long)okey(d2) << 32) | (unsigned)m;
                    if (key > last && key < bestp) bestp = key;
                }
                unsigned long long mn = wmin64(bestp);
                if (lane == k) sel = mn;
                last = mn;
            }
        }

        // winners on lanes 0..15: exact-diff weights, outputs, degree halves
        float wgt = 0.0f;
        if (lane < KNN) {
            int j = (int)(unsigned)(sel & 0xFFFFFFFFull);
            float4 Q = spts[j];
            float dx = P.x - Q.x, dy = P.y - Q.y, dz = P.z - Q.z;
            float dist2 = (dx * dx + dy * dy) + dz * dz;            // numpy order
            wgt = expf(-(dist2 * 0.5f));
            size_t base = (size_t)rowg * KNN + lane;
            idx_out[base] = j;
            w_out[base]   = wgt;
            atomicAdd(&Dsum[(b << 12) + j], 0.5f * wgt);            // transpose half
        }
        float rs = wgt;
        for (int o = 32; o > 0; o >>= 1) rs += __shfl_xor(rs, o);
        if (lane == 0) atomicAdd(&Dsum[rowg], 0.5f * rs);           // outgoing half
    }
}

// ---------------------------------------------------------------------------
// Scatter: one thread per (row, k); computes d^{-1/2} on the fly and adds
// -0.5*w*s_n*s_j to (n,j) and (j,n). Self entry lands twice -> A[n,n]=w_self.
// ---------------------------------------------------------------------------
__global__ __launch_bounds__(256) void scatter_kernel(const int* __restrict__ idxb,
                                                      const float* __restrict__ wb,
                                                      const float* __restrict__ Dsum,
                                                      float* __restrict__ L) {
    int g   = blockIdx.x * 256 + threadIdx.x;     // 0..BN*K-1
    int row = g >> 4;
    int b   = row >> 12;
    int n   = row & (NPTS - 1);
    int j   = idxb[g];
    float sn = 1.0f / sqrtf(fmaxf(Dsum[row], 1e-6f));
    float sj = 1.0f / sqrtf(fmaxf(Dsum[(b << 12) + j], 1e-6f));
    float v  = -0.5f * wb[g] * sn * sj;
    float* Lb = L + (size_t)b * NPTS * NPTS;
    atomicAdd(Lb + (size_t)n * NPTS + j, v);
    atomicAdd(Lb + (size_t)j * NPTS + n, v);
}

// ---------------------------------------------------------------------------
extern "C" void kernel_launch(void* const* d_in, const int* in_sizes, int n_in,
                              void* d_out, int out_size, void* d_ws, size_t ws_size,
                              hipStream_t stream) {
    const float* xyz = (const float*)d_in[0];
    const int B  = in_sizes[0] / (3 * NPTS);            // 4
    const int BN = B * NPTS;                            // 16384

    // workspace: Dsum[BN] | idx[BN*K] | w[BN*K]  (~2.2 MB)
    float* Dsum = (float*)d_ws;
    int*   idxb = (int*)(Dsum + BN);
    float* wb   = (float*)(idxb + (size_t)BN * KNN);
    float* L    = (float*)d_out;

    size_t T4 = (size_t)B * NPTS * NPTS / 4;
    fill_kernel<<<8192, 256, 0, stream>>>((float4*)d_out, (float4*)Dsum, T4);
    knn_kernel<<<BN / RPBK, KT, 0, stream>>>(xyz, Dsum, idxb, wb);
    scatter_kernel<<<(BN * KNN) / 256, 256, 0, stream>>>(idxb, wb, Dsum, L);
}